// Round 8
// baseline (65.894 us; speedup 1.0000x reference)
//
#include <hip/hip_runtime.h>

// x: [128,8,32,32,32] f32  cw: [16,8,3,3,3] f32  cb: [16]  bias: [16]  out: [128]
// out[b] = (1/6750)*sum_{c,cells} maxpool2(conv_raw) + sum_c(cb[c]/2 + bias[c])
//
// R8 = R7's verified compute body (16x16x32 MFMA, Bw[9] (kd,kh)-bundles, tg=kw,
// in-lane 2x2x2 pooling, XOR swizzle ^((w>>3)&3)<<4) with:
//  - 2-deep register-pipelined ring staging: write batch pd+2 (issued 2 steps
//    ago -> vmcnt(8), never drain-to-0 in loop), issue batch pd+4 same slot.
//  - prep_w folded into the block (72 L2 dword loads/lane, once per block).
//  - s_setprio(1) around the MFMA cluster (4 independent blocks/CU).

using short8 = __attribute__((ext_vector_type(8))) short;
using f32x4  = __attribute__((ext_vector_type(4))) float;

__device__ __forceinline__ unsigned short f2bf_rn(float f) {
  unsigned u = __float_as_uint(f);
  return (unsigned short)((u + 0x7FFFu + ((u >> 16) & 1u)) >> 16);
}

__global__ __launch_bounds__(256, 4) void conv_fused(
    const float* __restrict__ x, const float* __restrict__ cw,
    float* __restrict__ partial) {
  __shared__ __align__(16) char lds[6 * 3072];  // 6-slab ring; slab=[r6][w32][ci8] bf16
  __shared__ float red[4];

  const int bid = blockIdx.x;                    // 1024 blocks
  const int swz = (bid & 7) * 128 + (bid >> 3);  // XCD-chunk, bijective
  const int b = swz >> 3, q = swz & 7;           // q: oh rows 4q..4q+3 (q=7: 2 rows)
  const int t = threadIdx.x, lane = t & 63, wv = t >> 6;
  const int nrows = (q == 7) ? 4 : 6;
  const int row0 = 4 * q;
  const int sites = nrows * 16;
  const float* xb = x + (size_t)b * 262144;

  const int m = lane & 15, tg = lane >> 4;

  // ---- B fragments rebuilt in-block (was prep_w kernel):
  //      Bw[g=kd*3+kh][lane] = w[co=m][ci=j][kd][kh][kw=tg]; tg==3 -> 0 ----
  short8 Bw[9];
#pragma unroll
  for (int g = 0; g < 9; ++g) {
    const int tgs = (tg < 3) ? tg : 0;  // safe addr for pad lanes
    const float* wp = cw + (g / 3) * 9 + (g % 3) * 3 + tgs;
    short8 o;
#pragma unroll
    for (int j = 0; j < 8; ++j) {
      const float v = wp[(m * 8 + j) * 27];
      o[j] = (tg < 3) ? (short)f2bf_rn(v) : (short)0;
    }
    Bw[g] = o;
  }

  // ---- staging decode: site = (plane-of-pair spl, local row sr, w-group swg) ----
  const bool sact = t < 2 * sites;
  const int spl = (t >= sites) ? 1 : 0;
  const int ss = sact ? (t - spl * sites) : 0;
  const int sr = ss >> 4, swg = ss & 15;
  const float* gsite = xb + (row0 + sr) * 32 + swg * 2;  // + plane*1024 + ci*32768

  auto issueB = [&](int pb, float2* v) {  // pb = plane base (2k)
    if (!sact) return;
    const float* gp = gsite + (pb + spl) * 1024;
#pragma unroll
    for (int ci = 0; ci < 8; ++ci) v[ci] = *(const float2*)(gp + ci * 32768);
  };
  auto writeB = [&](int ws0, const float2* v) {  // ws0 = slab base in {0,2,4}
    if (!sact) return;
    char* sb = lds + (ws0 + spl) * 3072 + sr * 512;
#pragma unroll
    for (int wi = 0; wi < 2; ++wi) {
      const int w = swg * 2 + wi;
      uint4 o;  // truncation bf16 pack [ci0..ci7] (verified R6/R7)
      o.x = __builtin_amdgcn_perm(__float_as_uint(((const float*)&v[1])[wi]),
                                  __float_as_uint(((const float*)&v[0])[wi]), 0x07060302u);
      o.y = __builtin_amdgcn_perm(__float_as_uint(((const float*)&v[3])[wi]),
                                  __float_as_uint(((const float*)&v[2])[wi]), 0x07060302u);
      o.z = __builtin_amdgcn_perm(__float_as_uint(((const float*)&v[5])[wi]),
                                  __float_as_uint(((const float*)&v[4])[wi]), 0x07060302u);
      o.w = __builtin_amdgcn_perm(__float_as_uint(((const float*)&v[7])[wi]),
                                  __float_as_uint(((const float*)&v[6])[wi]), 0x07060302u);
      *(uint4*)(sb + ((w * 16) ^ (((w >> 3) & 3) << 4))) = o;
    }
  };

  // ---- per-lane A addressing (verified R3/R7) ----
  const int w0 = m + tg;
  int w1 = m + 16 + tg; if (w1 > 31) w1 = 31;  // clamp hits only masked/pad lanes
  const int wb0 = (w0 * 16) ^ (((w0 >> 3) & 3) << 4);
  const int wb1 = (w1 * 16) ^ (((w1 >> 3) & 3) << 4);

  const bool docomp = (q < 7) || (wv < 2);
  const int op = (q < 7) ? (wv >> 1) : 0;
  const int c  = (q < 7) ? (wv & 1) : wv;
  const int wbase = (c ? wb1 : wb0) + (2 * op) * 512;

  // ---- prologue: batches b0..b1 written, b2..b3 in flight ----
  float2 bufA[8], bufB[8];
  issueB(0, bufA);   // planes 0,1
  issueB(2, bufB);   // planes 2,3
  writeB(0, bufA);   // slabs 0,1   (vmcnt keeps b1 in flight)
  issueB(4, bufA);   // planes 4,5
  writeB(2, bufB);   // slabs 2,3
  issueB(6, bufB);   // planes 6,7
  __syncthreads();

  // ---- main loop: write batch pd+2 (2-step-old loads), issue batch pd+4 ----
  float sum = 0.0f;
  int rs0 = 0;   // read slab base  (2pd)%6
  int wsl = 4;   // write slab base (2pd+4)%6
  int wpl = 8;   // issue plane base 2pd+8
  for (int pd = 0; pd < 15; ++pd) {
    if (pd <= 13) {
      float2* buf = (pd & 1) ? bufB : bufA;
      writeB(wsl, buf);
      if (pd <= 11) issueB(wpl, buf);
    }

    if (docomp) {
      int sl1 = rs0 + 1;
      int sl2 = rs0 + 2; if (sl2 >= 6) sl2 -= 6;
      int sl3 = rs0 + 3; if (sl3 >= 6) sl3 -= 6;
      const char* sbp[4] = {lds + rs0 * 3072 + wbase, lds + sl1 * 3072 + wbase,
                            lds + sl2 * 3072 + wbase, lds + sl3 * 3072 + wbase};
      f32x4 cc[2][2] = {};  // [od][s]
      __builtin_amdgcn_s_setprio(1);
#pragma unroll
      for (int p = 0; p < 4; ++p) {
#pragma unroll
        for (int rr = 0; rr < 4; ++rr) {
          const short8 a = *(const short8*)(sbp[p] + rr * 512);
          if (p < 3 && rr < 3)
            cc[0][0] = __builtin_amdgcn_mfma_f32_16x16x32_bf16(a, Bw[p * 3 + rr], cc[0][0], 0, 0, 0);
          if (p < 3 && rr > 0)
            cc[0][1] = __builtin_amdgcn_mfma_f32_16x16x32_bf16(a, Bw[p * 3 + rr - 1], cc[0][1], 0, 0, 0);
          if (p > 0 && rr < 3)
            cc[1][0] = __builtin_amdgcn_mfma_f32_16x16x32_bf16(a, Bw[(p - 1) * 3 + rr], cc[1][0], 0, 0, 0);
          if (p > 0 && rr > 0)
            cc[1][1] = __builtin_amdgcn_mfma_f32_16x16x32_bf16(a, Bw[(p - 1) * 3 + rr - 1], cc[1][1], 0, 0, 0);
        }
      }
      __builtin_amdgcn_s_setprio(0);
      // maxpool 2x2x2 fully in-lane; mask pw 15 (ow 30/31) of chunk1
#pragma unroll
      for (int p2 = 0; p2 < 2; ++p2) {
        float v = fmaxf(fmaxf(fmaxf(cc[0][0][2 * p2], cc[0][0][2 * p2 + 1]),
                              fmaxf(cc[0][1][2 * p2], cc[0][1][2 * p2 + 1])),
                        fmaxf(fmaxf(cc[1][0][2 * p2], cc[1][0][2 * p2 + 1]),
                              fmaxf(cc[1][1][2 * p2], cc[1][1][2 * p2 + 1])));
        const bool inval = (c == 1) && (tg == 3) && (p2 == 1);
        sum += inval ? 0.0f : v;
      }
    }

    __syncthreads();
    rs0 += 2; if (rs0 >= 6) rs0 -= 6;
    wsl += 2; if (wsl >= 6) wsl -= 6;
    wpl += 2;
  }

  // ---- block reduction ----
#pragma unroll
  for (int off = 32; off; off >>= 1) sum += __shfl_down(sum, off);
  if (lane == 0) red[wv] = sum;
  __syncthreads();
  if (t == 0) partial[b * 8 + q] = red[0] + red[1] + red[2] + red[3];
}

__global__ __launch_bounds__(128) void finalize(const float* __restrict__ partial,
                                                const float* __restrict__ cb,
                                                const float* __restrict__ bias,
                                                float* __restrict__ out) {
  const int b = threadIdx.x;  // 128 threads, 1 block
  float k = 0.0f;
#pragma unroll
  for (int c = 0; c < 16; ++c) k += cb[c] * 0.5f + bias[c];
  float s = 0.0f;
#pragma unroll
  for (int q = 0; q < 8; ++q) s += partial[b * 8 + q];
  out[b] = s * (1.0f / 6750.0f) + k;
}

extern "C" void kernel_launch(void* const* d_in, const int* in_sizes, int n_in,
                              void* d_out, int out_size, void* d_ws, size_t ws_size,
                              hipStream_t stream) {
  const float* x    = (const float*)d_in[0];
  const float* cw   = (const float*)d_in[1];
  const float* cb   = (const float*)d_in[2];
  const float* bias = (const float*)d_in[3];
  float* out = (float*)d_out;
  float* partial = (float*)d_ws;  // 1024 floats

  conv_fused<<<1024, 256, 0, stream>>>(x, cw, partial);
  finalize<<<1, 128, 0, stream>>>(partial, cb, bias, out);
}

// Round 9
// 61.616 us; speedup vs baseline: 1.0694x; 1.0694x over previous
//
#include <hip/hip_runtime.h>

// x: [128,8,32,32,32] f32  cw: [16,8,3,3,3] f32  cb: [16]  bias: [16]  out: [128]
// out[b] = (1/6750)*sum_{c,cells} maxpool2(conv_raw) + sum_c(cb[c]/2 + bias[c])
//
// R9 = R8 with the scratch bug fixed: buffer alternation is STATIC (explicit
// 2x-unrolled double-step with named bufA/bufB), so both staging batches live
// in VGPRs and writes wait with counted vmcnt(8), never drain-to-0 in loop.
// Compute body unchanged (16x16x32 MFMA, Bw[9] (kd,kh)-bundles, tg=kw, in-lane
// 2x2x2 pooling, XOR swizzle ^((w>>3)&3)<<4; verified R3/R5/R7, absmax 0.125).

using short8 = __attribute__((ext_vector_type(8))) short;
using f32x4  = __attribute__((ext_vector_type(4))) float;

__device__ __forceinline__ unsigned short f2bf_rn(float f) {
  unsigned u = __float_as_uint(f);
  return (unsigned short)((u + 0x7FFFu + ((u >> 16) & 1u)) >> 16);
}

__global__ __launch_bounds__(256, 4) void conv_fused(
    const float* __restrict__ x, const float* __restrict__ cw,
    float* __restrict__ partial) {
  __shared__ __align__(16) char lds[6 * 3072];  // 6-slab ring; slab=[r6][w32][ci8] bf16
  __shared__ float red[4];

  const int bid = blockIdx.x;                    // 1024 blocks = 4/CU exactly
  const int swz = (bid & 7) * 128 + (bid >> 3);  // XCD-chunk, bijective
  const int b = swz >> 3, q = swz & 7;           // q: oh rows 4q..4q+3 (q=7: 2 rows)
  const int t = threadIdx.x, lane = t & 63, wv = t >> 6;
  const int nrows = (q == 7) ? 4 : 6;
  const int row0 = 4 * q;
  const int sites = nrows * 16;
  const float* xb = x + (size_t)b * 262144;

  const int m = lane & 15, tg = lane >> 4;

  // ---- B fragments rebuilt in-block:
  //      Bw[g=kd*3+kh][lane] = w[co=m][ci=j][kd][kh][kw=tg]; tg==3 -> 0 ----
  short8 Bw[9];
#pragma unroll
  for (int g = 0; g < 9; ++g) {
    const int tgs = (tg < 3) ? tg : 0;  // safe addr for pad lanes
    const float* wp = cw + (g / 3) * 9 + (g % 3) * 3 + tgs;
    short8 o;
#pragma unroll
    for (int j = 0; j < 8; ++j) {
      const float v = wp[(m * 8 + j) * 27];
      o[j] = (tg < 3) ? (short)f2bf_rn(v) : (short)0;
    }
    Bw[g] = o;
  }

  // ---- staging decode: site = (plane-of-pair spl, local row sr, w-group swg) ----
  const bool sact = t < 2 * sites;
  const int spl = (t >= sites) ? 1 : 0;
  const int ss = sact ? (t - spl * sites) : 0;
  const int sr = ss >> 4, swg = ss & 15;
  const float* gsite = xb + (row0 + sr) * 32 + swg * 2;  // + plane*1024 + ci*32768

  auto issueB = [&](int pb, float2* v) {  // pb = plane base (2k)
    if (!sact) return;
    const float* gp = gsite + (pb + spl) * 1024;
#pragma unroll
    for (int ci = 0; ci < 8; ++ci) v[ci] = *(const float2*)(gp + ci * 32768);
  };
  auto writeB = [&](int ws0, const float2* v) {  // ws0 = slab base in {0,2,4}
    if (!sact) return;
    char* sb = lds + (ws0 + spl) * 3072 + sr * 512;
#pragma unroll
    for (int wi = 0; wi < 2; ++wi) {
      const int w = swg * 2 + wi;
      uint4 o;  // truncation bf16 pack [ci0..ci7] (verified R6/R7)
      o.x = __builtin_amdgcn_perm(__float_as_uint(((const float*)&v[1])[wi]),
                                  __float_as_uint(((const float*)&v[0])[wi]), 0x07060302u);
      o.y = __builtin_amdgcn_perm(__float_as_uint(((const float*)&v[3])[wi]),
                                  __float_as_uint(((const float*)&v[2])[wi]), 0x07060302u);
      o.z = __builtin_amdgcn_perm(__float_as_uint(((const float*)&v[5])[wi]),
                                  __float_as_uint(((const float*)&v[4])[wi]), 0x07060302u);
      o.w = __builtin_amdgcn_perm(__float_as_uint(((const float*)&v[7])[wi]),
                                  __float_as_uint(((const float*)&v[6])[wi]), 0x07060302u);
      *(uint4*)(sb + ((w * 16) ^ (((w >> 3) & 3) << 4))) = o;
    }
  };

  // ---- per-lane A addressing (verified R3/R7) ----
  const int w0 = m + tg;
  int w1 = m + 16 + tg; if (w1 > 31) w1 = 31;  // clamp hits only masked/pad lanes
  const int wb0 = (w0 * 16) ^ (((w0 >> 3) & 3) << 4);
  const int wb1 = (w1 * 16) ^ (((w1 >> 3) & 3) << 4);

  const bool docomp = (q < 7) || (wv < 2);
  const int op = (q < 7) ? (wv >> 1) : 0;
  const int c  = (q < 7) ? (wv & 1) : wv;
  const int wbase = (c ? wb1 : wb0) + (2 * op) * 512;

  float sum = 0.0f;
  auto compute = [&](int rs0) {
    if (!docomp) return;
    int sl1 = rs0 + 1;
    int sl2 = rs0 + 2; if (sl2 >= 6) sl2 -= 6;
    int sl3 = rs0 + 3; if (sl3 >= 6) sl3 -= 6;
    const char* sbp[4] = {lds + rs0 * 3072 + wbase, lds + sl1 * 3072 + wbase,
                          lds + sl2 * 3072 + wbase, lds + sl3 * 3072 + wbase};
    f32x4 cc[2][2] = {};  // [od][s]
    __builtin_amdgcn_s_setprio(1);
#pragma unroll
    for (int p = 0; p < 4; ++p) {
#pragma unroll
      for (int rr = 0; rr < 4; ++rr) {
        const short8 a = *(const short8*)(sbp[p] + rr * 512);
        if (p < 3 && rr < 3)
          cc[0][0] = __builtin_amdgcn_mfma_f32_16x16x32_bf16(a, Bw[p * 3 + rr], cc[0][0], 0, 0, 0);
        if (p < 3 && rr > 0)
          cc[0][1] = __builtin_amdgcn_mfma_f32_16x16x32_bf16(a, Bw[p * 3 + rr - 1], cc[0][1], 0, 0, 0);
        if (p > 0 && rr < 3)
          cc[1][0] = __builtin_amdgcn_mfma_f32_16x16x32_bf16(a, Bw[(p - 1) * 3 + rr], cc[1][0], 0, 0, 0);
        if (p > 0 && rr > 0)
          cc[1][1] = __builtin_amdgcn_mfma_f32_16x16x32_bf16(a, Bw[(p - 1) * 3 + rr - 1], cc[1][1], 0, 0, 0);
      }
    }
    __builtin_amdgcn_s_setprio(0);
#pragma unroll
    for (int p2 = 0; p2 < 2; ++p2) {
      float v = fmaxf(fmaxf(fmaxf(cc[0][0][2 * p2], cc[0][0][2 * p2 + 1]),
                            fmaxf(cc[0][1][2 * p2], cc[0][1][2 * p2 + 1])),
                      fmaxf(fmaxf(cc[1][0][2 * p2], cc[1][0][2 * p2 + 1]),
                            fmaxf(cc[1][1][2 * p2], cc[1][1][2 * p2 + 1])));
      const bool inval = (c == 1) && (tg == 3) && (p2 == 1);  // pw 15 invalid
      sum += inval ? 0.0f : v;
    }
  };

  // ---- prologue: slabs 0-3 written; bufA=planes(4,5), bufB=planes(6,7) in flight ----
  float2 bufA[8], bufB[8];
  issueB(0, bufA);
  issueB(2, bufB);
  writeB(0, bufA);   // vmcnt(8): bufB stays in flight
  issueB(4, bufA);
  writeB(2, bufB);
  issueB(6, bufB);
  __syncthreads();

  // ---- main loop: 7 static double-steps (pd = 2k even->bufA, odd->bufB) ----
  int rs0 = 0;   // read slab base  (2pd)%6
  int wsl = 4;   // write slab base (2pd+4)%6
  int wpl = 8;   // issue plane base 2pd+8 (valid while <= 30)
#pragma unroll 1
  for (int pp = 0; pp < 7; ++pp) {
    // even pd
    writeB(wsl, bufA);
    if (wpl <= 30) issueB(wpl, bufA);
    compute(rs0);
    __syncthreads();
    rs0 += 2; if (rs0 >= 6) rs0 -= 6;
    wsl += 2; if (wsl >= 6) wsl -= 6;
    wpl += 2;
    // odd pd
    writeB(wsl, bufB);
    if (wpl <= 30) issueB(wpl, bufB);
    compute(rs0);
    __syncthreads();
    rs0 += 2; if (rs0 >= 6) rs0 -= 6;
    wsl += 2; if (wsl >= 6) wsl -= 6;
    wpl += 2;
  }
  compute(rs0);  // pd = 14: compute only

  // ---- block reduction ----
#pragma unroll
  for (int off = 32; off; off >>= 1) sum += __shfl_down(sum, off);
  if (lane == 0) red[wv] = sum;
  __syncthreads();
  if (t == 0) partial[b * 8 + q] = red[0] + red[1] + red[2] + red[3];
}

__global__ __launch_bounds__(128) void finalize(const float* __restrict__ partial,
                                                const float* __restrict__ cb,
                                                const float* __restrict__ bias,
                                                float* __restrict__ out) {
  const int b = threadIdx.x;  // 128 threads, 1 block
  float k = 0.0f;
#pragma unroll
  for (int c = 0; c < 16; ++c) k += cb[c] * 0.5f + bias[c];
  float s = 0.0f;
#pragma unroll
  for (int q = 0; q < 8; ++q) s += partial[b * 8 + q];
  out[b] = s * (1.0f / 6750.0f) + k;
}

extern "C" void kernel_launch(void* const* d_in, const int* in_sizes, int n_in,
                              void* d_out, int out_size, void* d_ws, size_t ws_size,
                              hipStream_t stream) {
  const float* x    = (const float*)d_in[0];
  const float* cw   = (const float*)d_in[1];
  const float* cb   = (const float*)d_in[2];
  const float* bias = (const float*)d_in[3];
  float* out = (float*)d_out;
  float* partial = (float*)d_ws;  // 1024 floats

  conv_fused<<<1024, 256, 0, stream>>>(x, cw, partial);
  finalize<<<1, 128, 0, stream>>>(partial, cb, bias, out);
}